// Round 15
// baseline (396.526 us; speedup 1.0000x reference)
//
#include <hip/hip_runtime.h>
#include <hip/hip_bf16.h>

#define B_ 4
#define T_ 128
#define HID 2560
#define NH 8
#define NKV 4
#define HD 256
#define INTER 10240
#define MROWS 512
#define EPS 1e-6f

typedef float f32x4 __attribute__((ext_vector_type(4)));
typedef __bf16 bf16x8 __attribute__((ext_vector_type(8)));

__device__ __forceinline__ unsigned short f2bf(float f){
  unsigned int u = __builtin_bit_cast(unsigned int, f);
  u += 0x7fffu + ((u >> 16) & 1u);
  return (unsigned short)(u >> 16);
}
__device__ __forceinline__ float bf2f(unsigned short u){
  unsigned int x = ((unsigned int)u) << 16;
  return __builtin_bit_cast(float, x);
}
__device__ __forceinline__ unsigned int cvtpk(float lo, float hi){
  unsigned int r;
  asm("v_cvt_pk_bf16_f32 %0, %1, %2" : "=v"(r) : "v"(lo), "v"(hi));
  return r;
}
__device__ __forceinline__ void glds16(const void* g, void* l){
  __builtin_amdgcn_global_load_lds(
      (const __attribute__((address_space(1))) void*)g,
      (__attribute__((address_space(3))) void*)l, 16, 0, 0);
}

__device__ __forceinline__ float bsum256(float v, float* buf){
  #pragma unroll
  for (int o = 32; o; o >>= 1) v += __shfl_xor(v, o);
  __syncthreads();
  if ((threadIdx.x & 63) == 0) buf[threadIdx.x >> 6] = v;
  __syncthreads();
  return buf[0] + buf[1] + buf[2] + buf[3];
}

// A is stored K-TILE-PACKED: A_p[k>>5][row][k&31] (bf16).

// ---------------- K1: input RMSNorm -> packed bf16 ----------------
__global__ __launch_bounds__(256) void rms_in(
    const float* __restrict__ x, const float* __restrict__ w,
    unsigned short* __restrict__ out)
{
  __shared__ float buf[4];
  const int r = blockIdx.x, tid = threadIdx.x;
  const float* xp = x + (size_t)r * HID;
  float v[10]; float ss = 0.f;
  #pragma unroll
  for (int j = 0; j < 10; j++){ v[j] = xp[tid + j*256]; ss += v[j]*v[j]; }
  ss = bsum256(ss, buf);
  float s = rsqrtf(ss * (1.f/HID) + EPS);
  #pragma unroll
  for (int j = 0; j < 10; j++){
    int i = tid + j*256;
    out[((size_t)(i >> 5) * MROWS + r) * 32 + (i & 31)] = f2bf(v[j] * s * (1.f + w[i]));
  }
}

// ---------------- GEMM: C[split][512][N](bf16) = A_packed(bf16) * B(fp32,[N][K])^T ----
// FULL-M tile: 512M x 128N per block, 512 threads (8 waves, 4m x 2n,
// wave-tile 128x64). HALVES per-CU requested bytes per FLOP vs 256x128/2-blk
// (A duplication eliminated; A shared through LDS).
// A: glds->LDS 2-deep (32KB/tile), XOR chunk swizzle f(row)=(row>>1)&3 on
//    glds SOURCE and frag read (exact 2-way spread = free).
// B: glds->LDS 4-deep (16KB/tile fp32), chunk^(row&7) both sides (R14 proven).
// 128KB LDS total, 1 block/CU. Counted vmcnt per step; raw barriers.
__global__ __launch_bounds__(512, 1) void gemm_big(
    const unsigned short* __restrict__ Ap,   // packed [K/32][512][32]
    const float* __restrict__ B0,
    const float* __restrict__ B1,
    int n_hi,
    unsigned short* __restrict__ C,
    int N, int K, int klen)
{
  __shared__ char As[2 * 32768];
  __shared__ char Bs[4 * 16384];
  const int tid = threadIdx.x;
  const int bid = ((gridDim.x & 7) == 0)
      ? ((blockIdx.x & 7) * ((int)gridDim.x >> 3) + (blockIdx.x >> 3))
      : blockIdx.x;
  const int bn = bid << 7;
  const int kt0 = (blockIdx.y * klen) >> 5;
  const int nt = klen >> 5;

  const int w = tid >> 6, l = tid & 63;
  const int q = w & 3;        // m-quadrant (128 rows)
  const int h = w >> 2;       // n-half (64 cols)
  const int fr = l & 15, kq = l >> 4;

  const float* Bb = (bn < n_hi) ? B0 : B1;
  const int bnr = (bn < n_hi) ? bn : (bn - n_hi);

  f32x4 acc[8][4];
  #pragma unroll
  for (int i = 0; i < 8; i++)
    #pragma unroll
    for (int j = 0; j < 4; j++)
      #pragma unroll
      for (int e = 0; e < 4; e++) acc[i][j][e] = 0.f;

  // A stage: 4 glds/wave. LDS linear row = w*64 + c*16 + (l>>2), chunk l&3.
  // Source chunk j = (l&3) ^ ((l>>3)&3)  [= (row>>1)&3].
#define GLDS_A(tt, slot) { \
  char* dst = As + ((slot) << 15) + (w << 12); \
  const size_t kbase = (size_t)(kt0 + (tt)) * MROWS; \
  _Pragma("unroll") for (int c = 0; c < 4; c++){ \
    int row = (w << 6) + (c << 4) + (l >> 2); \
    int j = (l & 3) ^ ((l >> 3) & 3); \
    const unsigned short* src = Ap + (kbase + row) * 32 + (j << 3); \
    glds16(src, dst + (c << 10)); } }
  // B stage: 2 glds/wave. row = w*16 + g*8 + (l>>3), source chunk (l&7)^(row&7).
#define GLDS_B(tt, slot) { \
  char* dst = Bs + ((slot) << 14) + (w << 11); \
  const int ktf = (kt0 + (tt)) << 5; \
  _Pragma("unroll") for (int g = 0; g < 2; g++){ \
    int row = (w << 4) + (g << 3) + (l >> 3); \
    int j = (l & 7) ^ ((l >> 3) & 7); \
    const float* src = Bb + (size_t)(bnr + row) * K + ktf + (j << 2); \
    glds16(src, dst + (g << 10)); } }
#define VM(n) asm volatile("s_waitcnt vmcnt(" #n ")" ::: "memory")
#define COMPUTE(sa, sb) { \
  const char* ab = As + ((sa) << 15); \
  const char* bb = Bs + ((sb) << 14); \
  bf16x8 af[8], bfv[4]; \
  const int ach = (kq ^ ((fr >> 1) & 3)) << 4; \
  _Pragma("unroll") for (int mi = 0; mi < 8; mi++){ \
    int row = (q << 7) + mi*16 + fr; \
    af[mi] = *(const bf16x8*)(ab + (row << 6) + ach); } \
  const int sw = fr & 7; \
  _Pragma("unroll") for (int ni = 0; ni < 4; ni++){ \
    int row = (h << 6) + ni*16 + fr; \
    const char* rb = bb + (row << 7); \
    f32x4 lo = *(const f32x4*)(rb + ((( 2*kq   ) ^ sw) << 4)); \
    f32x4 hi = *(const f32x4*)(rb + ((( 2*kq+1 ) ^ sw) << 4)); \
    union { unsigned int u[4]; bf16x8 v; } pk; \
    pk.u[0] = cvtpk(lo[0], lo[1]); pk.u[1] = cvtpk(lo[2], lo[3]); \
    pk.u[2] = cvtpk(hi[0], hi[1]); pk.u[3] = cvtpk(hi[2], hi[3]); \
    bfv[ni] = pk.v; } \
  __builtin_amdgcn_s_setprio(1); \
  _Pragma("unroll") for (int mi = 0; mi < 8; mi++) \
    _Pragma("unroll") for (int ni = 0; ni < 4; ni++) \
      acc[mi][ni] = __builtin_amdgcn_mfma_f32_16x16x32_bf16(af[mi], bfv[ni], acc[mi][ni], 0, 0, 0); \
  __builtin_amdgcn_s_setprio(0); }
#define MIN_(a,b) ((a)<(b)?(a):(b))

  // prologue: A(0), B(0..2) in flight (per-wave ops: 4 + 2+2+2 = 10)
  GLDS_A(0, 0);
  GLDS_B(0, 0); GLDS_B(1, 1); GLDS_B(2, 2);
  VM(4);                                // A(0),B(0) landed; B(1),B(2) in flight
  __builtin_amdgcn_s_barrier();

  for (int t = 0; t < nt; t++) {
    // slots (t+1)&1 / (t+3)&3 were last read at step t-1 -> WAR-safe post-barrier
    GLDS_A(MIN_(t+1, nt-1), (t+1) & 1);
    GLDS_B(MIN_(t+3, nt-1), (t+3) & 3);
    COMPUTE(t & 1, t & 3);
    VM(2);                              // A(t+1),B(t+1) landed; B(t+3) in flight
    __builtin_amdgcn_s_barrier();
  }
#undef GLDS_A
#undef GLDS_B
#undef VM
#undef COMPUTE
#undef MIN_

  unsigned short* Cp = C + (size_t)blockIdx.y * MROWS * N;
  #pragma unroll
  for (int mi = 0; mi < 8; mi++) {
    #pragma unroll
    for (int ni = 0; ni < 4; ni++) {
      int m = (q << 7) + mi*16 + kq*4;
      int n = bn + (h << 6) + ni*16 + fr;
      #pragma unroll
      for (int i = 0; i < 4; i++)
        Cp[(size_t)(m + i) * N + n] = f2bf(acc[mi][ni][i]);
    }
  }
}

// ---------------- K3: sum qkv splits (8, bf16), QK-norm, RoPE, scatter ----------------
__global__ __launch_bounds__(64) void qkv_post(
    const unsigned short* __restrict__ qkvp,   // [8][512][4096] bf16
    const float* __restrict__ fcos, const float* __restrict__ fsin,
    const float* __restrict__ qnw, const float* __restrict__ knw,
    float* __restrict__ qout, float* __restrict__ kT, float* __restrict__ vout)
{
  const int row = blockIdx.x;
  const int hh  = blockIdx.y;
  const int b = row >> 7, t = row & 127;
  const int l = threadIdx.x;
  const size_t MS = (size_t)MROWS * 4096;
  const unsigned short* src = qkvp + (size_t)row * 4096 + hh * 256;
  float x[4];
  #pragma unroll
  for (int j = 0; j < 4; j++){
    int d = l + j*64;
    float v = 0.f;
    #pragma unroll
    for (int s = 0; s < 8; s++) v += bf2f(src[d + s*MS]);
    x[j] = v;
  }
  if (hh >= 12) {
    float* vp = vout + ((size_t)(b*NKV + (hh-12)) * T_ + t) * HD;
    #pragma unroll
    for (int j = 0; j < 4; j++) vp[l + j*64] = x[j];
    return;
  }
  float ss = x[0]*x[0] + x[1]*x[1] + x[2]*x[2] + x[3]*x[3];
  #pragma unroll
  for (int o = 32; o; o >>= 1) ss += __shfl_xor(ss, o);
  float r = rsqrtf(ss * (1.f/HD) + EPS);
  const float* nw = (hh < 8) ? qnw : knw;
  #pragma unroll
  for (int j = 0; j < 4; j++){ int d = l + j*64; x[j] = x[j] * r * (1.f + nw[d]); }
  float c0 = fcos[t*128 + l],      s0 = fsin[t*128 + l];
  float c1 = fcos[t*128 + l + 64], s1 = fsin[t*128 + l + 64];
  float y0 = x[0]*c0 - x[2]*s0;
  float y2 = x[0]*s0 + x[2]*c0;
  float y1 = x[1]*c1 - x[3]*s1;
  float y3 = x[1]*s1 + x[3]*c1;
  if (hh < 8) {
    float* qp = qout + ((size_t)(b*NH + hh) * T_ + t) * HD;
    const float sc = 0.0625f;
    qp[l] = y0*sc; qp[l+64] = y1*sc; qp[l+128] = y2*sc; qp[l+192] = y3*sc;
  } else {
    float* kp = kT + (size_t)(b*NKV + (hh-8)) * HD * T_;
    kp[(size_t)(l)*T_ + t] = y0;  kp[(size_t)(l+64)*T_ + t] = y1;
    kp[(size_t)(l+128)*T_ + t] = y2; kp[(size_t)(l+192)*T_ + t] = y3;
  }
}

// ---------------- K4: causal attention; writes att_b PACKED for o-proj ----------------
__global__ __launch_bounds__(128) void attn_fwd(
    const float* __restrict__ q, const float* __restrict__ kT,
    const float* __restrict__ V, unsigned short* __restrict__ att)
{
  const int id = blockIdx.x;
  const int t = id & 127;
  const int h = (id >> 7) & 7;
  const int b = id >> 10;
  const int kvh = h >> 1;
  const int tid = threadIdx.x;
  __shared__ float qs[256];
  __shared__ float sc[128];
  __shared__ float red[128];
  const float* qp = q + (size_t)id * HD;
  qs[tid] = qp[tid]; qs[tid + 128] = qp[tid + 128];
  __syncthreads();
  const float* kp = kT + (size_t)(b*NKV + kvh) * HD * T_;
  float dot = 0.f;
  const bool valid = (tid <= t);
  if (valid) {
    #pragma unroll 8
    for (int d = 0; d < 256; d++) dot += qs[d] * kp[(size_t)d*T_ + tid];
  }
  float score = valid ? 50.f * tanhf(dot * 0.02f) : -3.0e38f;
  sc[tid] = score; red[tid] = score;
  __syncthreads();
  for (int o = 64; o; o >>= 1){ if (tid < o) red[tid] = fmaxf(red[tid], red[tid+o]); __syncthreads(); }
  float m = red[0];
  __syncthreads();
  float p = valid ? __expf(score - m) : 0.f;
  sc[tid] = p; red[tid] = p;
  __syncthreads();
  for (int o = 64; o; o >>= 1){ if (tid < o) red[tid] += red[tid+o]; __syncthreads(); }
  float inv = 1.f / red[0];
  const float* vp = V + (size_t)(b*NKV + kvh) * T_ * HD;
  float a0 = 0.f, a1 = 0.f;
  for (int s = 0; s <= t; s++){
    float ps = sc[s];
    a0 += ps * vp[(size_t)s*HD + tid];
    a1 += ps * vp[(size_t)s*HD + tid + 128];
  }
  const int row = b*T_ + t;
  const int c0 = h*256 + tid, c1 = c0 + 128;
  att[((size_t)(c0 >> 5) * MROWS + row) * 32 + (c0 & 31)] = f2bf(a0 * inv);
  att[((size_t)(c1 >> 5) * MROWS + row) * 32 + (c1 & 31)] = f2bf(a1 * inv);
}

// ---------------- K6: sum o splits (16, bf16), post-attn norm + residual, pre-ffw norm -> packed bf16 ----------------
__global__ __launch_bounds__(256) void post_attn_k(
    const unsigned short* __restrict__ op, const float* __restrict__ hs,
    const float* __restrict__ wpost, const float* __restrict__ wpre,
    float* __restrict__ h2, unsigned short* __restrict__ xout)
{
  __shared__ float buf[4];
  const int r = blockIdx.x, tid = threadIdx.x;
  const size_t MS = (size_t)MROWS * HID;
  float o[10]; float ss = 0.f;
  #pragma unroll
  for (int j = 0; j < 10; j++){
    size_t i = (size_t)r*HID + tid + j*256;
    float v = 0.f;
    #pragma unroll
    for (int s = 0; s < 16; s++) v += bf2f(op[i + s*MS]);
    o[j] = v; ss += v*v;
  }
  ss = bsum256(ss, buf);
  float s = rsqrtf(ss*(1.f/HID) + EPS);
  float h[10]; float s2 = 0.f;
  #pragma unroll
  for (int j = 0; j < 10; j++){
    int i = tid + j*256;
    float hv = hs[(size_t)r*HID + i] + o[j]*s*(1.f + wpost[i]);
    h[j] = hv; h2[(size_t)r*HID + i] = hv; s2 += hv*hv;
  }
  s2 = bsum256(s2, buf);
  float sc2 = rsqrtf(s2*(1.f/HID) + EPS);
  #pragma unroll
  for (int j = 0; j < 10; j++){
    int i = tid + j*256;
    xout[((size_t)(i >> 5) * MROWS + r) * 32 + (i & 31)] = f2bf(h[j]*sc2*(1.f + wpre[i]));
  }
}

// ---------------- K9: act = gelu_tanh(sum gate) * (sum up) -> packed bf16 ----------------
__global__ __launch_bounds__(256) void act_fuse(
    const unsigned short* __restrict__ gu,   // [4][512][20480] bf16
    unsigned short* __restrict__ act)        // packed [320][512][32] bf16
{
  const int r = blockIdx.x;
  const int c0 = blockIdx.y * 2560;
  const size_t MS = (size_t)MROWS * 20480;
  const unsigned short* rowp = gu + (size_t)r * 20480;
  for (int c = c0 + threadIdx.x; c < c0 + 2560; c += 256){
    float g = 0.f, u = 0.f;
    #pragma unroll
    for (int s = 0; s < 4; s++){
      g += bf2f(rowp[s*MS + c]);
      u += bf2f(rowp[s*MS + c + INTER]);
    }
    float tt = tanhf(0.7978845608f * (g + 0.044715f * g*g*g));
    float ge = 0.5f * g * (1.f + tt);
    act[((size_t)(c >> 5) * MROWS + r) * 32 + (c & 31)] = f2bf(ge * u);
  }
}

// ---------------- K11: sum down splits (32, bf16), final norm + residual ----------------
__global__ __launch_bounds__(256) void final_k(
    const unsigned short* __restrict__ dp, const float* __restrict__ h2,
    const float* __restrict__ w, float* __restrict__ out)
{
  __shared__ float buf[4];
  const int r = blockIdx.x, tid = threadIdx.x;
  const size_t MS = (size_t)MROWS * HID;
  float m[10]; float ss = 0.f;
  #pragma unroll
  for (int j = 0; j < 10; j++){
    size_t i = (size_t)r*HID + tid + j*256;
    float v = 0.f;
    #pragma unroll
    for (int s = 0; s < 32; s++) v += bf2f(dp[i + s*MS]);
    m[j] = v; ss += v*v;
  }
  ss = bsum256(ss, buf);
  float s = rsqrtf(ss*(1.f/HID) + EPS);
  #pragma unroll
  for (int j = 0; j < 10; j++){
    int i = tid + j*256;
    out[(size_t)r*HID + i] = h2[(size_t)r*HID + i] + m[j]*s*(1.f + w[i]);
  }
}

extern "C" void kernel_launch(void* const* d_in, const int* in_sizes, int n_in,
                              void* d_out, int out_size, void* d_ws, size_t ws_size,
                              hipStream_t stream)
{
  const float* hs     = (const float*)d_in[0];
  const float* fcos   = (const float*)d_in[1];
  const float* fsin   = (const float*)d_in[2];
  const float* w_qkv  = (const float*)d_in[8];
  const float* w_o    = (const float*)d_in[9];
  const float* qnw    = (const float*)d_in[10];
  const float* knw    = (const float*)d_in[11];
  const float* in_ln  = (const float*)d_in[12];
  const float* w_post = (const float*)d_in[13];
  const float* w_pre  = (const float*)d_in[14];
  const float* w_pffw = (const float*)d_in[15];
  const float* w_gate = (const float*)d_in[16];
  const float* w_up   = (const float*)d_in[17];
  const float* w_down = (const float*)d_in[18];
  float* out = (float*)d_out;

  char* p = (char*)d_ws;
  auto alloc = [&](size_t bytes)->void*{ void* r = p; p += (bytes + 255) & ~(size_t)255; return r; };
  void* P0 = alloc((size_t)4*MROWS*20480*2);   // qkv_p bf16 [8][512][4096] then gu_p bf16 [4][512][20480]
  void* P1 = alloc((size_t)32*MROWS*HID*2);    // o_p bf16 [16] then down_p bf16 [32]
  unsigned short* h_b   = (unsigned short*)alloc((size_t)MROWS*HID*2);
  float* qbuf           = (float*)alloc((size_t)B_*NH*T_*HD*4);
  float* kT             = (float*)alloc((size_t)B_*NKV*HD*T_*4);
  float* vbuf           = (float*)alloc((size_t)B_*NKV*T_*HD*4);
  unsigned short* att_b = (unsigned short*)alloc((size_t)MROWS*2048*2);
  float* h2             = (float*)alloc((size_t)MROWS*HID*4);
  unsigned short* x_b   = (unsigned short*)alloc((size_t)MROWS*HID*2);
  unsigned short* act_b = (unsigned short*)alloc((size_t)MROWS*INTER*2);

  unsigned short* qkv_p = (unsigned short*)P0;
  unsigned short* gu_p  = (unsigned short*)P0;
  unsigned short* o_p   = (unsigned short*)P1;
  unsigned short* down_p= (unsigned short*)P1;

  rms_in<<<MROWS, 256, 0, stream>>>(hs, in_ln, h_b);
  // qkv: N=4096 -> 32 n-tiles x 8 splits (klen 320, nt 10)
  gemm_big<<<dim3(32, 8), 512, 0, stream>>>(h_b, w_qkv, w_qkv, 1<<30, qkv_p, 4096, 2560, 320);
  qkv_post<<<dim3(MROWS, 16), 64, 0, stream>>>(qkv_p, fcos, fsin, qnw, knw, qbuf, kT, vbuf);
  attn_fwd<<<B_*NH*T_, 128, 0, stream>>>(qbuf, kT, vbuf, att_b);
  // o: N=2560 -> 20 n-tiles x 16 splits (klen 128, nt 4)
  gemm_big<<<dim3(20, 16), 512, 0, stream>>>(att_b, w_o, w_o, 1<<30, o_p, 2560, 2048, 128);
  post_attn_k<<<MROWS, 256, 0, stream>>>(o_p, hs, w_post, w_pre, h2, x_b);
  // fused gate+up: N=20480 -> 160 n-tiles x 4 splits (klen 640, nt 20)
  gemm_big<<<dim3(160, 4), 512, 0, stream>>>(x_b, w_gate, w_up, 10240, gu_p, 20480, 2560, 640);
  act_fuse<<<dim3(MROWS, 4), 256, 0, stream>>>(gu_p, act_b);
  // down: N=2560 -> 20 n-tiles x 32 splits (klen 320, nt 10)
  gemm_big<<<dim3(20, 32), 512, 0, stream>>>(act_b, w_down, w_down, 1<<30, down_p, 2560, 10240, 320);
  final_k<<<MROWS, 256, 0, stream>>>(down_p, h2, w_pffw, out);
}

// Round 16
// 345.513 us; speedup vs baseline: 1.1476x; 1.1476x over previous
//
#include <hip/hip_runtime.h>
#include <hip/hip_bf16.h>

#define B_ 4
#define T_ 128
#define HID 2560
#define NH 8
#define NKV 4
#define HD 256
#define INTER 10240
#define MROWS 512
#define EPS 1e-6f

typedef float f32x4 __attribute__((ext_vector_type(4)));
typedef __bf16 bf16x8 __attribute__((ext_vector_type(8)));

__device__ __forceinline__ unsigned short f2bf(float f){
  unsigned int u = __builtin_bit_cast(unsigned int, f);
  u += 0x7fffu + ((u >> 16) & 1u);
  return (unsigned short)(u >> 16);
}
__device__ __forceinline__ float bf2f(unsigned short u){
  unsigned int x = ((unsigned int)u) << 16;
  return __builtin_bit_cast(float, x);
}
__device__ __forceinline__ unsigned int cvtpk(float lo, float hi){
  unsigned int r;
  asm("v_cvt_pk_bf16_f32 %0, %1, %2" : "=v"(r) : "v"(lo), "v"(hi));
  return r;
}

__device__ __forceinline__ float bsum256(float v, float* buf){
  #pragma unroll
  for (int o = 32; o; o >>= 1) v += __shfl_xor(v, o);
  __syncthreads();
  if ((threadIdx.x & 63) == 0) buf[threadIdx.x >> 6] = v;
  __syncthreads();
  return buf[0] + buf[1] + buf[2] + buf[3];
}

// A is stored K-TILE-PACKED: A_p[k>>5][row][k&31] (bf16). One wave frag-load
// = 1024 contiguous bytes -> perfectly coalesced, straight from L2 to regs.

// ---------------- K1: input RMSNorm -> packed bf16 ----------------
__global__ __launch_bounds__(256) void rms_in(
    const float* __restrict__ x, const float* __restrict__ w,
    unsigned short* __restrict__ out)
{
  __shared__ float buf[4];
  const int r = blockIdx.x, tid = threadIdx.x;
  const float* xp = x + (size_t)r * HID;
  float v[10]; float ss = 0.f;
  #pragma unroll
  for (int j = 0; j < 10; j++){ v[j] = xp[tid + j*256]; ss += v[j]*v[j]; }
  ss = bsum256(ss, buf);
  float s = rsqrtf(ss * (1.f/HID) + EPS);
  #pragma unroll
  for (int j = 0; j < 10; j++){
    int i = tid + j*256;
    out[((size_t)(i >> 5) * MROWS + r) * 32 + (i & 31)] = f2bf(v[j] * s * (1.f + w[i]));
  }
}

// ---------------- GEMM: C[split][M][N](bf16) = A_packed(bf16) * B(fp32,[N][K])^T ----------
// R13 structure (best measured): 256Mx128N tile, wave-tile 128x64, BK=32.
// A: direct-to-reg from packed layout (coalesced), double reg-set aR/aS.
// B: LDS 2x8KB bf16 (cvt before write), XOR-swizzled, 2-deep reg prefetch.
// Raw barriers (lgkmcnt only). split_major=1: 1D grid where blockIdx%8 ->
// split-pair -> same-split blocks co-XCD (A-slice lives in that XCD's L2;
// kills the L3 A-amplification that made `down` 2x slower per step).
__global__ __launch_bounds__(256, 2) void gemm_big(
    const unsigned short* __restrict__ Ap,   // packed [K/32][512][32]
    const float* __restrict__ B0,
    const float* __restrict__ B1,
    int n_hi,
    unsigned short* __restrict__ C,
    int N, int K, int klen, int split_major)
{
  __shared__ char Bs[2][128*64];   // 8KB each
  const int tid = threadIdx.x;
  int bid, split;
  if (split_major) {
    // 1D grid of 640: rid%8 keys the XCD; XCD owns a pair of splits (16 total)
    int rid = blockIdx.x;
    int i = rid & 7, t2 = rid >> 3;
    split = i*2 + (t2 & 1);
    bid = t2 >> 1;                 // 0..39 -> (bm, bn)
  } else {
    bid = (blockIdx.x & 7) * ((int)gridDim.x >> 3) + (blockIdx.x >> 3);
    split = blockIdx.y;
  }
  const int bm = (bid & 1) << 8;
  const int bn = (bid >> 1) << 7;
  const int kt0 = (split * klen) >> 5;
  const int nt = klen >> 5;        // even for all shapes used

  const int srow = tid >> 1, shalf = tid & 1;
  const float* Bb = (bn < n_hi) ? B0 : B1;
  const int bnr = (bn < n_hi) ? bn : (bn - n_hi);
  const float* BpG = Bb + (size_t)(bnr + srow) * K + (kt0 << 5) + (shalf << 4);

  const int wave = tid >> 6, lane = tid & 63;
  const int wm = (wave & 1) << 7;
  const int wn = (wave >> 1) << 6;
  const int fr = lane & 15, kq = lane >> 4;
  const int bslot = ((kq ^ ((fr >> 1) & 3)) << 4);   // B read-side swizzle
  const int brsw = (srow >> 1) & 3;                  // B write-side swizzle
  const int s0 = (((2*shalf)     ^ brsw) << 4);
  const int s1 = (((2*shalf + 1) ^ brsw) << 4);

  const unsigned short* ApL = Ap + ((size_t)kt0 * MROWS + bm + wm + fr) * 32 + kq * 8;

  f32x4 acc[8][4];
  #pragma unroll
  for (int i = 0; i < 8; i++)
    #pragma unroll
    for (int j = 0; j < 4; j++)
      #pragma unroll
      for (int e = 0; e < 4; e++) acc[i][j][e] = 0.f;

  uint4 aR[8], aS[8];
  float4 rb0, rb1, rb2, rb3, sb0, sb1, sb2, sb3;

#define ISSUE_A(dst, tt) { const unsigned short* ap = ApL + (size_t)(tt) * 16384; \
  dst[0] = *(const uint4*)(ap);        dst[1] = *(const uint4*)(ap + 512); \
  dst[2] = *(const uint4*)(ap + 1024); dst[3] = *(const uint4*)(ap + 1536); \
  dst[4] = *(const uint4*)(ap + 2048); dst[5] = *(const uint4*)(ap + 2560); \
  dst[6] = *(const uint4*)(ap + 3072); dst[7] = *(const uint4*)(ap + 3584); }
#define LOAD_B(p0,p1,p2,p3, tt) { const float* bp = BpG + ((tt) << 5); \
  p0 = *(const float4*)(bp);     p1 = *(const float4*)(bp + 4); \
  p2 = *(const float4*)(bp + 8); p3 = *(const float4*)(bp + 12); }
#define WRITE_B(cur, b0,b1,b2,b3) { uint4 w0, w1; \
  w0.x = cvtpk(b0.x,b0.y); w0.y = cvtpk(b0.z,b0.w); \
  w0.z = cvtpk(b1.x,b1.y); w0.w = cvtpk(b1.z,b1.w); \
  w1.x = cvtpk(b2.x,b2.y); w1.y = cvtpk(b2.z,b2.w); \
  w1.z = cvtpk(b3.x,b3.y); w1.w = cvtpk(b3.z,b3.w); \
  char* bbase = &Bs[cur][srow*64]; \
  *(uint4*)(bbase + s0) = w0; \
  *(uint4*)(bbase + s1) = w1; }
#define BAR() { asm volatile("s_waitcnt lgkmcnt(0)" ::: "memory"); \
  __builtin_amdgcn_s_barrier(); }
#define COMPUTE(cur, aset) { const char* bb = Bs[cur]; \
  bf16x8 bfv[4]; \
  _Pragma("unroll") for (int ni = 0; ni < 4; ni++) \
    bfv[ni] = *(const bf16x8*)(bb + ((wn + ni*16 + fr) << 6) + bslot); \
  __builtin_amdgcn_s_setprio(1); \
  _Pragma("unroll") for (int mi = 0; mi < 8; mi++){ \
    bf16x8 af = __builtin_bit_cast(bf16x8, aset[mi]); \
    _Pragma("unroll") for (int ni = 0; ni < 4; ni++) \
      acc[mi][ni] = __builtin_amdgcn_mfma_f32_16x16x32_bf16(af, bfv[ni], acc[mi][ni], 0, 0, 0); } \
  __builtin_amdgcn_s_setprio(0); }

  // prologue: A(0), B(0), B(1) in flight
  ISSUE_A(aR, 0);
  LOAD_B(rb0,rb1,rb2,rb3, 0);
  LOAD_B(sb0,sb1,sb2,sb3, 1);

  for (int t = 0; t < nt; t += 2) {
    ISSUE_A(aS, t + 1);                       // stays in flight past barrier
    WRITE_B(0, rb0,rb1,rb2,rb3);              // waits ONLY B(t)
    BAR();
    if (t + 2 < nt) LOAD_B(rb0,rb1,rb2,rb3, t + 2);
    COMPUTE(0, aR);                           // A(t) issued 1 iter ago
    if (t + 2 < nt) ISSUE_A(aR, t + 2);
    WRITE_B(1, sb0,sb1,sb2,sb3);              // waits ONLY B(t+1)
    BAR();
    if (t + 3 < nt) LOAD_B(sb0,sb1,sb2,sb3, t + 3);
    COMPUTE(1, aS);
  }
#undef ISSUE_A
#undef LOAD_B
#undef WRITE_B
#undef BAR
#undef COMPUTE

  unsigned short* Cp = C + (size_t)split * MROWS * N;
  #pragma unroll
  for (int mi = 0; mi < 8; mi++) {
    #pragma unroll
    for (int ni = 0; ni < 4; ni++) {
      int m = bm + wm + mi*16 + kq*4;
      int n = bn + wn + ni*16 + fr;
      #pragma unroll
      for (int i = 0; i < 4; i++)
        Cp[(size_t)(m + i) * N + n] = f2bf(acc[mi][ni][i]);
    }
  }
}

// ---------------- K3: sum qkv splits (8, bf16), QK-norm, RoPE, scatter ----------------
__global__ __launch_bounds__(64) void qkv_post(
    const unsigned short* __restrict__ qkvp,   // [8][512][4096] bf16
    const float* __restrict__ fcos, const float* __restrict__ fsin,
    const float* __restrict__ qnw, const float* __restrict__ knw,
    float* __restrict__ qout, float* __restrict__ kT, float* __restrict__ vout)
{
  const int row = blockIdx.x;
  const int hh  = blockIdx.y;
  const int b = row >> 7, t = row & 127;
  const int l = threadIdx.x;
  const size_t MS = (size_t)MROWS * 4096;
  const unsigned short* src = qkvp + (size_t)row * 4096 + hh * 256;
  float x[4];
  #pragma unroll
  for (int j = 0; j < 4; j++){
    int d = l + j*64;
    float v = 0.f;
    #pragma unroll
    for (int s = 0; s < 8; s++) v += bf2f(src[d + s*MS]);
    x[j] = v;
  }
  if (hh >= 12) {
    float* vp = vout + ((size_t)(b*NKV + (hh-12)) * T_ + t) * HD;
    #pragma unroll
    for (int j = 0; j < 4; j++) vp[l + j*64] = x[j];
    return;
  }
  float ss = x[0]*x[0] + x[1]*x[1] + x[2]*x[2] + x[3]*x[3];
  #pragma unroll
  for (int o = 32; o; o >>= 1) ss += __shfl_xor(ss, o);
  float r = rsqrtf(ss * (1.f/HD) + EPS);
  const float* nw = (hh < 8) ? qnw : knw;
  #pragma unroll
  for (int j = 0; j < 4; j++){ int d = l + j*64; x[j] = x[j] * r * (1.f + nw[d]); }
  float c0 = fcos[t*128 + l],      s0 = fsin[t*128 + l];
  float c1 = fcos[t*128 + l + 64], s1 = fsin[t*128 + l + 64];
  float y0 = x[0]*c0 - x[2]*s0;
  float y2 = x[0]*s0 + x[2]*c0;
  float y1 = x[1]*c1 - x[3]*s1;
  float y3 = x[1]*s1 + x[3]*c1;
  if (hh < 8) {
    float* qp = qout + ((size_t)(b*NH + hh) * T_ + t) * HD;
    const float sc = 0.0625f;
    qp[l] = y0*sc; qp[l+64] = y1*sc; qp[l+128] = y2*sc; qp[l+192] = y3*sc;
  } else {
    float* kp = kT + (size_t)(b*NKV + (hh-8)) * HD * T_;
    kp[(size_t)(l)*T_ + t] = y0;  kp[(size_t)(l+64)*T_ + t] = y1;
    kp[(size_t)(l+128)*T_ + t] = y2; kp[(size_t)(l+192)*T_ + t] = y3;
  }
}

// ---------------- K4: causal attention; writes att_b PACKED for o-proj ----------------
__global__ __launch_bounds__(128) void attn_fwd(
    const float* __restrict__ q, const float* __restrict__ kT,
    const float* __restrict__ V, unsigned short* __restrict__ att)
{
  const int id = blockIdx.x;
  const int t = id & 127;
  const int h = (id >> 7) & 7;
  const int b = id >> 10;
  const int kvh = h >> 1;
  const int tid = threadIdx.x;
  __shared__ float qs[256];
  __shared__ float sc[128];
  __shared__ float red[128];
  const float* qp = q + (size_t)id * HD;
  qs[tid] = qp[tid]; qs[tid + 128] = qp[tid + 128];
  __syncthreads();
  const float* kp = kT + (size_t)(b*NKV + kvh) * HD * T_;
  float dot = 0.f;
  const bool valid = (tid <= t);
  if (valid) {
    #pragma unroll 8
    for (int d = 0; d < 256; d++) dot += qs[d] * kp[(size_t)d*T_ + tid];
  }
  float score = valid ? 50.f * tanhf(dot * 0.02f) : -3.0e38f;
  sc[tid] = score; red[tid] = score;
  __syncthreads();
  for (int o = 64; o; o >>= 1){ if (tid < o) red[tid] = fmaxf(red[tid], red[tid+o]); __syncthreads(); }
  float m = red[0];
  __syncthreads();
  float p = valid ? __expf(score - m) : 0.f;
  sc[tid] = p; red[tid] = p;
  __syncthreads();
  for (int o = 64; o; o >>= 1){ if (tid < o) red[tid] += red[tid+o]; __syncthreads(); }
  float inv = 1.f / red[0];
  const float* vp = V + (size_t)(b*NKV + kvh) * T_ * HD;
  float a0 = 0.f, a1 = 0.f;
  for (int s = 0; s <= t; s++){
    float ps = sc[s];
    a0 += ps * vp[(size_t)s*HD + tid];
    a1 += ps * vp[(size_t)s*HD + tid + 128];
  }
  const int row = b*T_ + t;
  const int c0 = h*256 + tid, c1 = c0 + 128;
  att[((size_t)(c0 >> 5) * MROWS + row) * 32 + (c0 & 31)] = f2bf(a0 * inv);
  att[((size_t)(c1 >> 5) * MROWS + row) * 32 + (c1 & 31)] = f2bf(a1 * inv);
}

// ---------------- K6: sum o splits (16, bf16), post-attn norm + residual, pre-ffw norm -> packed bf16 ----------------
__global__ __launch_bounds__(256) void post_attn_k(
    const unsigned short* __restrict__ op, const float* __restrict__ hs,
    const float* __restrict__ wpost, const float* __restrict__ wpre,
    float* __restrict__ h2, unsigned short* __restrict__ xout)
{
  __shared__ float buf[4];
  const int r = blockIdx.x, tid = threadIdx.x;
  const size_t MS = (size_t)MROWS * HID;
  float o[10]; float ss = 0.f;
  #pragma unroll
  for (int j = 0; j < 10; j++){
    size_t i = (size_t)r*HID + tid + j*256;
    float v = 0.f;
    #pragma unroll
    for (int s = 0; s < 16; s++) v += bf2f(op[i + s*MS]);
    o[j] = v; ss += v*v;
  }
  ss = bsum256(ss, buf);
  float s = rsqrtf(ss*(1.f/HID) + EPS);
  float h[10]; float s2 = 0.f;
  #pragma unroll
  for (int j = 0; j < 10; j++){
    int i = tid + j*256;
    float hv = hs[(size_t)r*HID + i] + o[j]*s*(1.f + wpost[i]);
    h[j] = hv; h2[(size_t)r*HID + i] = hv; s2 += hv*hv;
  }
  s2 = bsum256(s2, buf);
  float sc2 = rsqrtf(s2*(1.f/HID) + EPS);
  #pragma unroll
  for (int j = 0; j < 10; j++){
    int i = tid + j*256;
    xout[((size_t)(i >> 5) * MROWS + r) * 32 + (i & 31)] = f2bf(h[j]*sc2*(1.f + wpre[i]));
  }
}

// ---------------- K9: act = gelu_tanh(sum gate) * (sum up) -> packed bf16 ----------------
__global__ __launch_bounds__(256) void act_fuse(
    const unsigned short* __restrict__ gu,   // [4][512][20480] bf16
    unsigned short* __restrict__ act)        // packed [320][512][32] bf16
{
  const int r = blockIdx.x;
  const int c0 = blockIdx.y * 2560;
  const size_t MS = (size_t)MROWS * 20480;
  const unsigned short* rowp = gu + (size_t)r * 20480;
  for (int c = c0 + threadIdx.x; c < c0 + 2560; c += 256){
    float g = 0.f, u = 0.f;
    #pragma unroll
    for (int s = 0; s < 4; s++){
      g += bf2f(rowp[s*MS + c]);
      u += bf2f(rowp[s*MS + c + INTER]);
    }
    float tt = tanhf(0.7978845608f * (g + 0.044715f * g*g*g));
    float ge = 0.5f * g * (1.f + tt);
    act[((size_t)(c >> 5) * MROWS + r) * 32 + (c & 31)] = f2bf(ge * u);
  }
}

// ---------------- K11: sum down splits (16, bf16), final norm + residual ----------------
__global__ __launch_bounds__(256) void final_k(
    const unsigned short* __restrict__ dp, const float* __restrict__ h2,
    const float* __restrict__ w, float* __restrict__ out)
{
  __shared__ float buf[4];
  const int r = blockIdx.x, tid = threadIdx.x;
  const size_t MS = (size_t)MROWS * HID;
  float m[10]; float ss = 0.f;
  #pragma unroll
  for (int j = 0; j < 10; j++){
    size_t i = (size_t)r*HID + tid + j*256;
    float v = 0.f;
    #pragma unroll
    for (int s = 0; s < 16; s++) v += bf2f(dp[i + s*MS]);
    m[j] = v; ss += v*v;
  }
  ss = bsum256(ss, buf);
  float s = rsqrtf(ss*(1.f/HID) + EPS);
  #pragma unroll
  for (int j = 0; j < 10; j++){
    int i = tid + j*256;
    out[(size_t)r*HID + i] = h2[(size_t)r*HID + i] + m[j]*s*(1.f + w[i]);
  }
}

extern "C" void kernel_launch(void* const* d_in, const int* in_sizes, int n_in,
                              void* d_out, int out_size, void* d_ws, size_t ws_size,
                              hipStream_t stream)
{
  const float* hs     = (const float*)d_in[0];
  const float* fcos   = (const float*)d_in[1];
  const float* fsin   = (const float*)d_in[2];
  const float* w_qkv  = (const float*)d_in[8];
  const float* w_o    = (const float*)d_in[9];
  const float* qnw    = (const float*)d_in[10];
  const float* knw    = (const float*)d_in[11];
  const float* in_ln  = (const float*)d_in[12];
  const float* w_post = (const float*)d_in[13];
  const float* w_pre  = (const float*)d_in[14];
  const float* w_pffw = (const float*)d_in[15];
  const float* w_gate = (const float*)d_in[16];
  const float* w_up   = (const float*)d_in[17];
  const float* w_down = (const float*)d_in[18];
  float* out = (float*)d_out;

  char* p = (char*)d_ws;
  auto alloc = [&](size_t bytes)->void*{ void* r = p; p += (bytes + 255) & ~(size_t)255; return r; };
  // P0: qkv_p bf16 [8][512][4096] (33.5MB) then gu_p bf16 [4][512][20480] (84MB)
  void* P0 = alloc((size_t)4*MROWS*20480*2);
  // P1: o_p bf16 [16][512][2560] (42MB) then down_p bf16 [16][512][2560] (42MB)
  void* P1 = alloc((size_t)16*MROWS*HID*2);
  unsigned short* h_b   = (unsigned short*)alloc((size_t)MROWS*HID*2);
  float* qbuf           = (float*)alloc((size_t)B_*NH*T_*HD*4);
  float* kT             = (float*)alloc((size_t)B_*NKV*HD*T_*4);
  float* vbuf           = (float*)alloc((size_t)B_*NKV*T_*HD*4);
  unsigned short* att_b = (unsigned short*)alloc((size_t)MROWS*2048*2);
  float* h2             = (float*)alloc((size_t)MROWS*HID*4);
  unsigned short* x_b   = (unsigned short*)alloc((size_t)MROWS*HID*2);
  unsigned short* act_b = (unsigned short*)alloc((size_t)MROWS*INTER*2);

  unsigned short* qkv_p = (unsigned short*)P0;
  unsigned short* gu_p  = (unsigned short*)P0;
  unsigned short* o_p   = (unsigned short*)P1;
  unsigned short* down_p= (unsigned short*)P1;

  rms_in<<<MROWS, 256, 0, stream>>>(hs, in_ln, h_b);
  // qkv: M=512,N=4096,K=2560 -> 64 tiles x 8 splits (klen 320, nt 10)
  gemm_big<<<dim3(64, 8), 256, 0, stream>>>(h_b, w_qkv, w_qkv, 1<<30, qkv_p, 4096, 2560, 320, 0);
  qkv_post<<<dim3(MROWS, 16), 64, 0, stream>>>(qkv_p, fcos, fsin, qnw, knw, qbuf, kT, vbuf);
  attn_fwd<<<B_*NH*T_, 128, 0, stream>>>(qbuf, kT, vbuf, att_b);
  // o: M=512,N=2560,K=2048 -> 40 tiles x 16 splits (klen 128, nt 4)
  gemm_big<<<dim3(40, 16), 256, 0, stream>>>(att_b, w_o, w_o, 1<<30, o_p, 2560, 2048, 128, 0);
  post_attn_k<<<MROWS, 256, 0, stream>>>(o_p, hs, w_post, w_pre, h2, x_b);
  // fused gate+up: M=512,N=20480,K=2560 -> 320 tiles x 4 splits (klen 640, nt 20)
  gemm_big<<<dim3(320, 4), 256, 0, stream>>>(x_b, w_gate, w_up, 10240, gu_p, 20480, 2560, 640, 0);
  act_fuse<<<dim3(MROWS, 4), 256, 0, stream>>>(gu_p, act_b);
  // down: M=512,N=2560,K=10240 -> SPLIT-MAJOR 1D grid 640 = 40 tiles x 16 splits
  // (blockIdx%8 -> split-pair -> co-XCD A-slice reuse from L2)
  gemm_big<<<640, 256, 0, stream>>>(act_b, w_down, w_down, 1<<30, down_p, 2560, 10240, 640, 1);
  final_k<<<MROWS, 256, 0, stream>>>(down_p, h2, w_pffw, out);
}

// Round 17
// 334.561 us; speedup vs baseline: 1.1852x; 1.0327x over previous
//
#include <hip/hip_runtime.h>
#include <hip/hip_bf16.h>

#define B_ 4
#define T_ 128
#define HID 2560
#define NH 8
#define NKV 4
#define HD 256
#define INTER 10240
#define MROWS 512
#define EPS 1e-6f

typedef float f32x4 __attribute__((ext_vector_type(4)));
typedef __bf16 bf16x8 __attribute__((ext_vector_type(8)));

__device__ __forceinline__ unsigned short f2bf(float f){
  unsigned int u = __builtin_bit_cast(unsigned int, f);
  u += 0x7fffu + ((u >> 16) & 1u);
  return (unsigned short)(u >> 16);
}
__device__ __forceinline__ float bf2f(unsigned short u){
  unsigned int x = ((unsigned int)u) << 16;
  return __builtin_bit_cast(float, x);
}
__device__ __forceinline__ unsigned int cvtpk(float lo, float hi){
  unsigned int r;
  asm("v_cvt_pk_bf16_f32 %0, %1, %2" : "=v"(r) : "v"(lo), "v"(hi));
  return r;
}
__device__ __forceinline__ void glds16(const void* g, void* l){
  __builtin_amdgcn_global_load_lds(
      (const __attribute__((address_space(1))) void*)g,
      (__attribute__((address_space(3))) void*)l, 16, 0, 0);
}

__device__ __forceinline__ float bsum256(float v, float* buf){
  #pragma unroll
  for (int o = 32; o; o >>= 1) v += __shfl_xor(v, o);
  __syncthreads();
  if ((threadIdx.x & 63) == 0) buf[threadIdx.x >> 6] = v;
  __syncthreads();
  return buf[0] + buf[1] + buf[2] + buf[3];
}

// A is stored K-TILE-PACKED: A_p[k>>5][row][k&31] (bf16). One wave frag-load
// = 1024 contiguous bytes -> perfectly coalesced, straight from L2 to regs.

// ---------------- K1: input RMSNorm -> packed bf16 ----------------
__global__ __launch_bounds__(256) void rms_in(
    const float* __restrict__ x, const float* __restrict__ w,
    unsigned short* __restrict__ out)
{
  __shared__ float buf[4];
  const int r = blockIdx.x, tid = threadIdx.x;
  const float* xp = x + (size_t)r * HID;
  float v[10]; float ss = 0.f;
  #pragma unroll
  for (int j = 0; j < 10; j++){ v[j] = xp[tid + j*256]; ss += v[j]*v[j]; }
  ss = bsum256(ss, buf);
  float s = rsqrtf(ss * (1.f/HID) + EPS);
  #pragma unroll
  for (int j = 0; j < 10; j++){
    int i = tid + j*256;
    out[((size_t)(i >> 5) * MROWS + r) * 32 + (i & 31)] = f2bf(v[j] * s * (1.f + w[i]));
  }
}

// ---------------- GEMM: C[split][M][N](bf16) = A_packed(bf16) * B(fp32,[N][K])^T ----------
// BK=64 EXPERIMENT: halves the K-step count (the one axis all prior
// variants held constant; tests the fixed-latency-per-step hypothesis).
// 256Mx128N tile, wave-tile 128x64, 4 waves.
// A: direct-to-reg, 16 frags/step (two packed-32 tiles), single set issued at
//    step top (covered by co-resident block + reads/cvt).
// B: fp32 glds -> 2-slot 64KB LDS ring; chunk^(row&7) involution on source
//    and read (2-way banks = free). glds(t+2) into the just-read slot AFTER
//    the read-barrier (WAR-safe). Clamped tail issues keep vmcnt exact.
__global__ __launch_bounds__(256, 2) void gemm_big(
    const unsigned short* __restrict__ Ap,   // packed [K/32][512][32]
    const float* __restrict__ B0,
    const float* __restrict__ B1,
    int n_hi,
    unsigned short* __restrict__ C,
    int N, int K, int klen, int split_major)
{
  __shared__ char Bs[2][128*256];   // fp32 B tile: 128 rows x 256B = 32KB each
  const int tid = threadIdx.x;
  int bid, split;
  if (split_major) {
    int rid = blockIdx.x;
    int i = rid & 7, t2 = rid >> 3;
    split = i*2 + (t2 & 1);
    bid = t2 >> 1;
  } else {
    bid = (blockIdx.x & 7) * ((int)gridDim.x >> 3) + (blockIdx.x >> 3);
    split = blockIdx.y;
  }
  const int bm = (bid & 1) << 8;
  const int bn = (bid >> 1) << 7;
  const int kt0 = (split * klen) >> 6;     // BK=64 tile index
  const int nt = klen >> 6;                // >= 4 for all shapes used

  const int w = tid >> 6, l = tid & 63;
  const float* Bb = (bn < n_hi) ? B0 : B1;
  const int bnr = (bn < n_hi) ? bn : (bn - n_hi);

  const int wm = (w & 1) << 7;
  const int wn = (w >> 1) << 6;
  const int fr = l & 15, kq = l >> 4;

  // A frag base: packed-32 tile index = 2*(kt0+t)+kk
  const unsigned short* ApL = Ap + ((size_t)(kt0*2) * MROWS + bm + wm + fr) * 32 + kq * 8;

  f32x4 acc[8][4];
  #pragma unroll
  for (int i = 0; i < 8; i++)
    #pragma unroll
    for (int j = 0; j < 4; j++)
      #pragma unroll
      for (int e = 0; e < 4; e++) acc[i][j][e] = 0.f;

  uint4 ar[16];

#define ISSUE_A(tt) { \
  const unsigned short* a0 = ApL + (size_t)(2*(tt)) * 16384; \
  const unsigned short* a1 = a0 + 16384; \
  _Pragma("unroll") for (int mi = 0; mi < 8; mi++){ \
    ar[mi]     = *(const uint4*)(a0 + mi*512*4); \
    ar[8 + mi] = *(const uint4*)(a1 + mi*512*4); } }
// NOTE: mi*512*4 ushorts = mi*16 rows * 32 ush/row... see check below.
// row stride in packed tile = 32 ushorts; 16 rows = 512 ushorts.
// (mi*512*4 would be wrong -> use mi*512). Corrected in real macro below.
#undef ISSUE_A
#define ISSUE_A(tt) { \
  const unsigned short* a0 = ApL + (size_t)(2*(tt)) * 16384; \
  const unsigned short* a1 = a0 + 16384; \
  _Pragma("unroll") for (int mi = 0; mi < 8; mi++){ \
    ar[mi]     = *(const uint4*)(a0 + mi*512); \
    ar[8 + mi] = *(const uint4*)(a1 + mi*512); } }

// B glds: per wave 8 instr; instr g covers rows w*32+g*4+(l>>4), chunk l&15.
// LDS linear slot c holds global 16B-chunk j = c ^ (row&7).
#define GLDS_B(tt, slot) { \
  char* dst = Bs[slot] + (w << 13); \
  const int kf = (kt0 + (tt)) << 6; \
  _Pragma("unroll") for (int g = 0; g < 8; g++){ \
    int row = (w << 5) + (g << 2) + (l >> 4); \
    int j = (l & 15) ^ (row & 7); \
    const float* src = Bb + (size_t)(bnr + row) * K + kf + (j << 2); \
    glds16(src, dst + (g << 10)); } }
#define VM(n) asm volatile("s_waitcnt vmcnt(" #n ")" ::: "memory")
#define MIN_(a,b) ((a)<(b)?(a):(b))

  // prologue: B(0), B(1) in flight (16 glds/wave total)
  GLDS_B(0, 0);
  GLDS_B(1, 1);

  for (int t = 0; t < nt; t++) {
    const int cur = t & 1;
    ISSUE_A(t);                       // 16 vm ops
    VM(24);                           // ensure B(t) landed (t=0: pops B(0); steady: no-op)
    // read + cvt both k-halves from Bs[cur]
    bf16x8 bfv[2][4];
    #pragma unroll
    for (int kk = 0; kk < 2; kk++){
      #pragma unroll
      for (int ni = 0; ni < 4; ni++){
        int row = wn + ni*16 + fr;
        const char* rb = Bs[cur] + (row << 8);
        int c0 = kk*8 + kq*2;
        int sw = row & 7;
        f32x4 lo = *(const f32x4*)(rb + (((c0  ) ^ sw) << 4));
        f32x4 hi = *(const f32x4*)(rb + (((c0+1) ^ sw) << 4));
        union { unsigned int u[4]; bf16x8 v; } pk;
        pk.u[0] = cvtpk(lo[0], lo[1]); pk.u[1] = cvtpk(lo[2], lo[3]);
        pk.u[2] = cvtpk(hi[0], hi[1]); pk.u[3] = cvtpk(hi[2], hi[3]);
        bfv[kk][ni] = pk.v;
      }
    }
    asm volatile("s_waitcnt lgkmcnt(0)" ::: "memory");
    __builtin_amdgcn_s_barrier();     // all waves done reading Bs[cur]
    GLDS_B(MIN_(t+2, nt-1), cur);     // overwrite just-read slot (8 vm, clamped tail)
    __builtin_amdgcn_s_setprio(1);
    #pragma unroll
    for (int kk = 0; kk < 2; kk++)
      #pragma unroll
      for (int mi = 0; mi < 8; mi++){
        bf16x8 af = __builtin_bit_cast(bf16x8, ar[kk*8 + mi]);
        #pragma unroll
        for (int ni = 0; ni < 4; ni++)
          acc[mi][ni] = __builtin_amdgcn_mfma_f32_16x16x32_bf16(af, bfv[kk][ni], acc[mi][ni], 0, 0, 0);
      }
    __builtin_amdgcn_s_setprio(0);
    // compiler's A-wait (vmcnt<=8) already drained B(t+1); barrier for next read
    __builtin_amdgcn_s_barrier();
  }
#undef ISSUE_A
#undef GLDS_B
#undef VM
#undef MIN_

  unsigned short* Cp = C + (size_t)split * MROWS * N;
  #pragma unroll
  for (int mi = 0; mi < 8; mi++) {
    #pragma unroll
    for (int ni = 0; ni < 4; ni++) {
      int m = bm + wm + mi*16 + kq*4;
      int n = bn + wn + ni*16 + fr;
      #pragma unroll
      for (int i = 0; i < 4; i++)
        Cp[(size_t)(m + i) * N + n] = f2bf(acc[mi][ni][i]);
    }
  }
}

// ---------------- K3: sum qkv splits (8, bf16), QK-norm, RoPE, scatter ----------------
__global__ __launch_bounds__(64) void qkv_post(
    const unsigned short* __restrict__ qkvp,   // [8][512][4096] bf16
    const float* __restrict__ fcos, const float* __restrict__ fsin,
    const float* __restrict__ qnw, const float* __restrict__ knw,
    float* __restrict__ qout, float* __restrict__ kT, float* __restrict__ vout)
{
  const int row = blockIdx.x;
  const int hh  = blockIdx.y;
  const int b = row >> 7, t = row & 127;
  const int l = threadIdx.x;
  const size_t MS = (size_t)MROWS * 4096;
  const unsigned short* src = qkvp + (size_t)row * 4096 + hh * 256;
  float x[4];
  #pragma unroll
  for (int j = 0; j < 4; j++){
    int d = l + j*64;
    float v = 0.f;
    #pragma unroll
    for (int s = 0; s < 8; s++) v += bf2f(src[d + s*MS]);
    x[j] = v;
  }
  if (hh >= 12) {
    float* vp = vout + ((size_t)(b*NKV + (hh-12)) * T_ + t) * HD;
    #pragma unroll
    for (int j = 0; j < 4; j++) vp[l + j*64] = x[j];
    return;
  }
  float ss = x[0]*x[0] + x[1]*x[1] + x[2]*x[2] + x[3]*x[3];
  #pragma unroll
  for (int o = 32; o; o >>= 1) ss += __shfl_xor(ss, o);
  float r = rsqrtf(ss * (1.f/HD) + EPS);
  const float* nw = (hh < 8) ? qnw : knw;
  #pragma unroll
  for (int j = 0; j < 4; j++){ int d = l + j*64; x[j] = x[j] * r * (1.f + nw[d]); }
  float c0 = fcos[t*128 + l],      s0 = fsin[t*128 + l];
  float c1 = fcos[t*128 + l + 64], s1 = fsin[t*128 + l + 64];
  float y0 = x[0]*c0 - x[2]*s0;
  float y2 = x[0]*s0 + x[2]*c0;
  float y1 = x[1]*c1 - x[3]*s1;
  float y3 = x[1]*s1 + x[3]*c1;
  if (hh < 8) {
    float* qp = qout + ((size_t)(b*NH + hh) * T_ + t) * HD;
    const float sc = 0.0625f;
    qp[l] = y0*sc; qp[l+64] = y1*sc; qp[l+128] = y2*sc; qp[l+192] = y3*sc;
  } else {
    float* kp = kT + (size_t)(b*NKV + (hh-8)) * HD * T_;
    kp[(size_t)(l)*T_ + t] = y0;  kp[(size_t)(l+64)*T_ + t] = y1;
    kp[(size_t)(l+128)*T_ + t] = y2; kp[(size_t)(l+192)*T_ + t] = y3;
  }
}

// ---------------- K4: causal attention; writes att_b PACKED for o-proj ----------------
__global__ __launch_bounds__(128) void attn_fwd(
    const float* __restrict__ q, const float* __restrict__ kT,
    const float* __restrict__ V, unsigned short* __restrict__ att)
{
  const int id = blockIdx.x;
  const int t = id & 127;
  const int h = (id >> 7) & 7;
  const int b = id >> 10;
  const int kvh = h >> 1;
  const int tid = threadIdx.x;
  __shared__ float qs[256];
  __shared__ float sc[128];
  __shared__ float red[128];
  const float* qp = q + (size_t)id * HD;
  qs[tid] = qp[tid]; qs[tid + 128] = qp[tid + 128];
  __syncthreads();
  const float* kp = kT + (size_t)(b*NKV + kvh) * HD * T_;
  float dot = 0.f;
  const bool valid = (tid <= t);
  if (valid) {
    #pragma unroll 8
    for (int d = 0; d < 256; d++) dot += qs[d] * kp[(size_t)d*T_ + tid];
  }
  float score = valid ? 50.f * tanhf(dot * 0.02f) : -3.0e38f;
  sc[tid] = score; red[tid] = score;
  __syncthreads();
  for (int o = 64; o; o >>= 1){ if (tid < o) red[tid] = fmaxf(red[tid], red[tid+o]); __syncthreads(); }
  float m = red[0];
  __syncthreads();
  float p = valid ? __expf(score - m) : 0.f;
  sc[tid] = p; red[tid] = p;
  __syncthreads();
  for (int o = 64; o; o >>= 1){ if (tid < o) red[tid] += red[tid+o]; __syncthreads(); }
  float inv = 1.f / red[0];
  const float* vp = V + (size_t)(b*NKV + kvh) * T_ * HD;
  float a0 = 0.f, a1 = 0.f;
  for (int s = 0; s <= t; s++){
    float ps = sc[s];
    a0 += ps * vp[(size_t)s*HD + tid];
    a1 += ps * vp[(size_t)s*HD + tid + 128];
  }
  const int row = b*T_ + t;
  const int c0 = h*256 + tid, c1 = c0 + 128;
  att[((size_t)(c0 >> 5) * MROWS + row) * 32 + (c0 & 31)] = f2bf(a0 * inv);
  att[((size_t)(c1 >> 5) * MROWS + row) * 32 + (c1 & 31)] = f2bf(a1 * inv);
}

// ---------------- K6: sum o splits (8, bf16), post-attn norm + residual, pre-ffw norm -> packed bf16 ----------------
__global__ __launch_bounds__(256) void post_attn_k(
    const unsigned short* __restrict__ op, const float* __restrict__ hs,
    const float* __restrict__ wpost, const float* __restrict__ wpre,
    float* __restrict__ h2, unsigned short* __restrict__ xout)
{
  __shared__ float buf[4];
  const int r = blockIdx.x, tid = threadIdx.x;
  const size_t MS = (size_t)MROWS * HID;
  float o[10]; float ss = 0.f;
  #pragma unroll
  for (int j = 0; j < 10; j++){
    size_t i = (size_t)r*HID + tid + j*256;
    float v = 0.f;
    #pragma unroll
    for (int s = 0; s < 8; s++) v += bf2f(op[i + s*MS]);
    o[j] = v; ss += v*v;
  }
  ss = bsum256(ss, buf);
  float s = rsqrtf(ss*(1.f/HID) + EPS);
  float h[10]; float s2 = 0.f;
  #pragma unroll
  for (int j = 0; j < 10; j++){
    int i = tid + j*256;
    float hv = hs[(size_t)r*HID + i] + o[j]*s*(1.f + wpost[i]);
    h[j] = hv; h2[(size_t)r*HID + i] = hv; s2 += hv*hv;
  }
  s2 = bsum256(s2, buf);
  float sc2 = rsqrtf(s2*(1.f/HID) + EPS);
  #pragma unroll
  for (int j = 0; j < 10; j++){
    int i = tid + j*256;
    xout[((size_t)(i >> 5) * MROWS + r) * 32 + (i & 31)] = f2bf(h[j]*sc2*(1.f + wpre[i]));
  }
}

// ---------------- K9: act = gelu_tanh(sum gate) * (sum up) -> packed bf16 ----------------
__global__ __launch_bounds__(256) void act_fuse(
    const unsigned short* __restrict__ gu,   // [4][512][20480] bf16
    unsigned short* __restrict__ act)        // packed [320][512][32] bf16
{
  const int r = blockIdx.x;
  const int c0 = blockIdx.y * 2560;
  const size_t MS = (size_t)MROWS * 20480;
  const unsigned short* rowp = gu + (size_t)r * 20480;
  for (int c = c0 + threadIdx.x; c < c0 + 2560; c += 256){
    float g = 0.f, u = 0.f;
    #pragma unroll
    for (int s = 0; s < 4; s++){
      g += bf2f(rowp[s*MS + c]);
      u += bf2f(rowp[s*MS + c + INTER]);
    }
    float tt = tanhf(0.7978845608f * (g + 0.044715f * g*g*g));
    float ge = 0.5f * g * (1.f + tt);
    act[((size_t)(c >> 5) * MROWS + r) * 32 + (c & 31)] = f2bf(ge * u);
  }
}

// ---------------- K11: sum down splits (16, bf16), final norm + residual ----------------
__global__ __launch_bounds__(256) void final_k(
    const unsigned short* __restrict__ dp, const float* __restrict__ h2,
    const float* __restrict__ w, float* __restrict__ out)
{
  __shared__ float buf[4];
  const int r = blockIdx.x, tid = threadIdx.x;
  const size_t MS = (size_t)MROWS * HID;
  float m[10]; float ss = 0.f;
  #pragma unroll
  for (int j = 0; j < 10; j++){
    size_t i = (size_t)r*HID + tid + j*256;
    float v = 0.f;
    #pragma unroll
    for (int s = 0; s < 16; s++) v += bf2f(dp[i + s*MS]);
    m[j] = v; ss += v*v;
  }
  ss = bsum256(ss, buf);
  float s = rsqrtf(ss*(1.f/HID) + EPS);
  #pragma unroll
  for (int j = 0; j < 10; j++){
    int i = tid + j*256;
    out[(size_t)r*HID + i] = h2[(size_t)r*HID + i] + m[j]*s*(1.f + w[i]);
  }
}

extern "C" void kernel_launch(void* const* d_in, const int* in_sizes, int n_in,
                              void* d_out, int out_size, void* d_ws, size_t ws_size,
                              hipStream_t stream)
{
  const float* hs     = (const float*)d_in[0];
  const float* fcos   = (const float*)d_in[1];
  const float* fsin   = (const float*)d_in[2];
  const float* w_qkv  = (const float*)d_in[8];
  const float* w_o    = (const float*)d_in[9];
  const float* qnw    = (const float*)d_in[10];
  const float* knw    = (const float*)d_in[11];
  const float* in_ln  = (const float*)d_in[12];
  const float* w_post = (const float*)d_in[13];
  const float* w_pre  = (const float*)d_in[14];
  const float* w_pffw = (const float*)d_in[15];
  const float* w_gate = (const float*)d_in[16];
  const float* w_up   = (const float*)d_in[17];
  const float* w_down = (const float*)d_in[18];
  float* out = (float*)d_out;

  char* p = (char*)d_ws;
  auto alloc = [&](size_t bytes)->void*{ void* r = p; p += (bytes + 255) & ~(size_t)255; return r; };
  // P0: qkv_p bf16 [8][512][4096] (33.5MB) then gu_p bf16 [4][512][20480] (84MB)
  void* P0 = alloc((size_t)4*MROWS*20480*2);
  // P1: o_p bf16 [8][512][2560] then down_p bf16 [16][512][2560] (42MB)
  void* P1 = alloc((size_t)16*MROWS*HID*2);
  unsigned short* h_b   = (unsigned short*)alloc((size_t)MROWS*HID*2);
  float* qbuf           = (float*)alloc((size_t)B_*NH*T_*HD*4);
  float* kT             = (float*)alloc((size_t)B_*NKV*HD*T_*4);
  float* vbuf           = (float*)alloc((size_t)B_*NKV*T_*HD*4);
  unsigned short* att_b = (unsigned short*)alloc((size_t)MROWS*2048*2);
  float* h2             = (float*)alloc((size_t)MROWS*HID*4);
  unsigned short* x_b   = (unsigned short*)alloc((size_t)MROWS*HID*2);
  unsigned short* act_b = (unsigned short*)alloc((size_t)MROWS*INTER*2);

  unsigned short* qkv_p = (unsigned short*)P0;
  unsigned short* gu_p  = (unsigned short*)P0;
  unsigned short* o_p   = (unsigned short*)P1;
  unsigned short* down_p= (unsigned short*)P1;

  rms_in<<<MROWS, 256, 0, stream>>>(hs, in_ln, h_b);
  // qkv: M=512,N=4096,K=2560 -> 64 tiles x 8 splits (klen 320, nt 5)
  gemm_big<<<dim3(64, 8), 256, 0, stream>>>(h_b, w_qkv, w_qkv, 1<<30, qkv_p, 4096, 2560, 320, 0);
  qkv_post<<<dim3(MROWS, 16), 64, 0, stream>>>(qkv_p, fcos, fsin, qnw, knw, qbuf, kT, vbuf);
  attn_fwd<<<B_*NH*T_, 128, 0, stream>>>(qbuf, kT, vbuf, att_b);
  // o: M=512,N=2560,K=2048 -> 40 tiles x 8 splits (klen 256, nt 4)
  gemm_big<<<dim3(40, 8), 256, 0, stream>>>(att_b, w_o, w_o, 1<<30, o_p, 2560, 2048, 256, 0);
  post_attn_k<<<MROWS, 256, 0, stream>>>(o_p, hs, w_post, w_pre, h2, x_b);
  // fused gate+up: M=512,N=20480,K=2560 -> 320 tiles x 4 splits (klen 640, nt 10)
  gemm_big<<<dim3(320, 4), 256, 0, stream>>>(x_b, w_gate, w_up, 10240, gu_p, 20480, 2560, 640, 0);
  act_fuse<<<dim3(MROWS, 4), 256, 0, stream>>>(gu_p, act_b);
  // down: M=512,N=2560,K=10240 -> split-major 1D 640 = 40 tiles x 16 splits (klen 640, nt 10)
  gemm_big<<<640, 256, 0, stream>>>(act_b, w_down, w_down, 1<<30, down_p, 2560, 10240, 640, 1);
  final_k<<<MROWS, 256, 0, stream>>>(down_p, h2, w_pffw, out);
}